// Round 1
// baseline (223.050 us; speedup 1.0000x reference)
//
#include <hip/hip_runtime.h>
#include <stdint.h>
#include <math.h>

// Problem constants
#define NB_B 8
#define NB_S 512
#define NB_D 1024
#define NB_H 16
#define NB_HD 64
#define NP 196            // image patches: bidirectional prefix block
#define MTOT 4096         // B*S

// Workspace layout (offsets in bf16/short elements). Total 25165824 shorts = 48 MB.
#define OFF_XB 0
#define OFF_WQ 4194304
#define OFF_WK 5242880
#define OFF_WV 6291456
#define OFF_WO 7340032
#define OFF_Q  8388608
#define OFF_K  12582912
#define OFF_VT 16777216
#define OFF_CT 20971520

typedef __attribute__((ext_vector_type(8))) short bf16x8;
typedef __attribute__((ext_vector_type(4))) float f32x4;
typedef __attribute__((ext_vector_type(4))) short s16x4;

__device__ __forceinline__ short f2bf(float f) {
  union { float f; uint32_t u; } c; c.f = f;
  uint32_t r = (c.u + 0x7fffu + ((c.u >> 16) & 1u)) >> 16;   // RNE
  return (short)r;
}

__device__ __forceinline__ void async16(void* lds, const void* g) {
  // global -> LDS direct copy, 16B per lane; LDS dest = uniform base + lane*16
  __builtin_amdgcn_global_load_lds(
      (const __attribute__((address_space(1))) void*)g,
      (__attribute__((address_space(3))) void*)lds, 16, 0, 0);
}

// ---------------------------------------------------------------------------
// fp32 -> bf16 conversion for x and the 4 weight matrices (one fused launch).
// w_q gets the 1/sqrt(hd)=0.125 softmax scale folded in (exact pow2 in bf16).
// ---------------------------------------------------------------------------
__global__ __launch_bounds__(256) void cvt5(const float* __restrict__ x,
                                            const float* __restrict__ wq,
                                            const float* __restrict__ wk,
                                            const float* __restrict__ wv,
                                            const float* __restrict__ wo,
                                            short* __restrict__ ws) {
  int b = blockIdx.x, t = threadIdx.x;
  const float* src; short* dst; float scale;
  if (b < 4096) { src = x + b * 1024; dst = ws + OFF_XB + b * 1024; scale = 1.0f; }
  else {
    int wb = b - 4096, wi = wb >> 10, r = wb & 1023;
    switch (wi) {
      case 0:  src = wq + r * 1024; dst = ws + OFF_WQ + r * 1024; scale = 0.125f; break;
      case 1:  src = wk + r * 1024; dst = ws + OFF_WK + r * 1024; scale = 1.0f;   break;
      case 2:  src = wv + r * 1024; dst = ws + OFF_WV + r * 1024; scale = 1.0f;   break;
      default: src = wo + r * 1024; dst = ws + OFF_WO + r * 1024; scale = 1.0f;   break;
    }
  }
  int i = t << 2;
  float4 v = *(const float4*)(src + i);
  s16x4 o;
  o[0] = f2bf(v.x * scale); o[1] = f2bf(v.y * scale);
  o[2] = f2bf(v.z * scale); o[3] = f2bf(v.w * scale);
  *(s16x4*)(dst + i) = o;
}

// ---------------------------------------------------------------------------
// Fused QKV projection: y = xb @ W^T, both operands K-contiguous (gemm_bt).
// 128x128 tile, BK=32, 4 waves each computing 64x64 (4x4 of 16x16 MFMA).
// LDS is MFMA-frag swizzled: chunk(mb) = [lane][8 bf16] so global_load_lds's
// uniform-base+lane*16 lands each lane's A/B fragment contiguously.
// Epilogue scatters to Q,K: [B,H,S,hd]; V: transposed [B,H,hd,S].
// ---------------------------------------------------------------------------
__global__ __launch_bounds__(256, 2) void gemm_qkv(short* __restrict__ ws) {
  __shared__ __align__(16) short As[4096];   // 128x32 bf16
  __shared__ __align__(16) short Bs[4096];
  int bx = blockIdx.x;              // 0..767
  int wsel = bx >> 8;               // 0=Q 1=K 2=V
  int tile = bx & 255;
  int mt = tile >> 3, nt = tile & 7;
  int m0 = mt << 7, n0 = nt << 7;
  const short* A  = ws + OFF_XB;
  const short* Bw = ws + (wsel == 0 ? OFF_WQ : (wsel == 1 ? OFF_WK : OFF_WV));
  int t = threadIdx.x, lane = t & 63, wvi = t >> 6;
  int c = lane & 15, quad = lane >> 4;
  int wm = wvi >> 1, wn = wvi & 1;
  f32x4 acc[4][4] = {};

  for (int kk = 0; kk < 1024; kk += 32) {
#pragma unroll
    for (int i = 0; i < 2; ++i) {
      int ch = wvi * 2 + i;         // wave-uniform chunk id (mb / nb block)
      const short* ga = A  + (m0 + ch * 16 + c) * 1024 + kk + (quad << 3);
      async16(&As[ch << 9], ga);
      const short* gb = Bw + (n0 + ch * 16 + c) * 1024 + kk + (quad << 3);
      async16(&Bs[ch << 9], gb);
    }
    __syncthreads();                // drains vmcnt for global_load_lds
    bf16x8 af[4], bfr[4];
#pragma unroll
    for (int i = 0; i < 4; ++i) af[i]  = *(const bf16x8*)&As[((wm * 4 + i) * 64 + lane) * 8];
#pragma unroll
    for (int j = 0; j < 4; ++j) bfr[j] = *(const bf16x8*)&Bs[((wn * 4 + j) * 64 + lane) * 8];
#pragma unroll
    for (int i = 0; i < 4; ++i)
#pragma unroll
      for (int j = 0; j < 4; ++j)
        acc[i][j] = __builtin_amdgcn_mfma_f32_16x16x32_bf16(af[i], bfr[j], acc[i][j], 0, 0, 0);
    __syncthreads();                // protect LDS before next stage
  }

  short* outp = ws + (wsel == 0 ? OFF_Q : (wsel == 1 ? OFF_K : OFF_VT));
#pragma unroll
  for (int i = 0; i < 4; ++i) {
#pragma unroll
    for (int j = 0; j < 4; ++j) {
      int n = n0 + wn * 64 + j * 16 + c;        // output feature
      int h = n >> 6, d = n & 63;
      int mq = m0 + wm * 64 + i * 16 + quad * 4; // first of the 4 rows (reg dim)
      int bb = mq >> 9, s = mq & 511;
      if (wsel < 2) {
        // [B,H,S,hd]
#pragma unroll
        for (int r = 0; r < 4; ++r)
          outp[((bb * 16 + h) * 512 + (s + r)) * 64 + d] = f2bf(acc[i][j][r]);
      } else {
        // V transposed: [B,H,hd,S]; the 4 regs are 4 consecutive s -> 8B store
        s16x4 o;
#pragma unroll
        for (int r = 0; r < 4; ++r) o[r] = f2bf(acc[i][j][r]);
        *(s16x4*)&outp[((bb * 16 + h) * 64 + d) * 512 + s] = o;
      }
    }
  }
}

// ---------------------------------------------------------------------------
// Attention: one block = (batch*head, q-chunk of 128 rows); 4 waves x 2
// Q-tiles of 16 rows. K/V streamed from global (L2-resident, 64KB/head).
// Scores (already scaled by 0.125 via w_q) held in regs in MFMA C-layout:
// softmax over keys = 32 in-lane values + shfl_xor over the 16-lane group.
// P goes C-layout -> A-layout via a 1KB/wave LDS scratch written directly
// in A-frag-swizzled order (no barriers needed; per-wave private).
// Prefix-LM mask truncates the key loops (rows<196 need keys<196; else causal).
// ---------------------------------------------------------------------------
__global__ __launch_bounds__(256, 2) void attn(short* __restrict__ ws) {
  __shared__ __align__(16) short Pch[4 * 512];
  int bi = blockIdx.x;              // 0..511
  int bh = bi >> 2, qc = bi & 3;
  int t = threadIdx.x, lane = t & 63, wvi = t >> 6;
  int c = lane & 15, quad = lane >> 4;
  const short* Qh  = ws + OFF_Q  + bh * (512 * 64);
  const short* Kh  = ws + OFF_K  + bh * (512 * 64);
  const short* Vth = ws + OFF_VT + bh * (64 * 512);
  short* ctx = ws + OFF_CT;
  int b = bh >> 4, h = bh & 15;
  short* pch = &Pch[wvi * 512];

#pragma unroll
  for (int sub = 0; sub < 2; ++sub) {
    int qbase = qc * 128 + wvi * 32 + sub * 16;
    int kneed = (qbase + 16 > NP) ? (qbase + 16) : NP;   // keys needed by this tile
    int nbmax = (kneed + 15) >> 4;
    int kbmax = (kneed + 31) >> 5;

    // Q fragment (A-layout): row = lane&15, k = quad*8+j  (+32 for frag 1)
    bf16x8 aq0 = *(const bf16x8*)(Qh + (qbase + c) * 64 + (quad << 3));
    bf16x8 aq1 = *(const bf16x8*)(Qh + (qbase + c) * 64 + 32 + (quad << 3));

    // --- QK^T ---
    f32x4 sc[32];
#pragma unroll
    for (int nb = 0; nb < 32; ++nb) {
      if (nb < nbmax) {
        const short* kp = Kh + (nb * 16 + c) * 64 + (quad << 3);
        bf16x8 bk0 = *(const bf16x8*)kp;
        bf16x8 bk1 = *(const bf16x8*)(kp + 32);
        f32x4 s = {};
        s = __builtin_amdgcn_mfma_f32_16x16x32_bf16(aq0, bk0, s, 0, 0, 0);
        s = __builtin_amdgcn_mfma_f32_16x16x32_bf16(aq1, bk1, s, 0, 0, 0);
        sc[nb] = s;
      }
    }

    // --- mask + row max ---
    float mx[4] = {-3.0e38f, -3.0e38f, -3.0e38f, -3.0e38f};
#pragma unroll
    for (int nb = 0; nb < 32; ++nb) {
      if (nb < nbmax) {
        int key = nb * 16 + c;
#pragma unroll
        for (int r = 0; r < 4; ++r) {
          int row = qbase + quad * 4 + r;
          bool valid = (row < NP) ? (key < NP) : (key <= row);
          float v = valid ? sc[nb][r] : -INFINITY;
          sc[nb][r] = v;
          mx[r] = fmaxf(mx[r], v);
        }
      }
    }
#pragma unroll
    for (int r = 0; r < 4; ++r)
#pragma unroll
      for (int msk = 1; msk < 16; msk <<= 1)
        mx[r] = fmaxf(mx[r], __shfl_xor(mx[r], msk));

    // --- exp + row sum ---
    float sum[4] = {0.f, 0.f, 0.f, 0.f};
#pragma unroll
    for (int nb = 0; nb < 32; ++nb) {
      if (nb < nbmax) {
#pragma unroll
        for (int r = 0; r < 4; ++r) {
          float p = __expf(sc[nb][r] - mx[r]);   // exp(-inf)=0 handles mask
          sc[nb][r] = p;
          sum[r] += p;
        }
      }
    }
#pragma unroll
    for (int r = 0; r < 4; ++r)
#pragma unroll
      for (int msk = 1; msk < 16; msk <<= 1)
        sum[r] += __shfl_xor(sum[r], msk);

    // --- P @ V (per 32-key chunk: C-layout -> A-layout via LDS) ---
    f32x4 acc[4] = {};
#pragma unroll
    for (int kb = 0; kb < 16; ++kb) {
      if (kb < kbmax) {
#pragma unroll
        for (int tt = 0; tt < 2; ++tt) {
          int nb = kb * 2 + tt;
          int q2 = (tt << 1) | (c >> 3), j = c & 7;   // dest quad', j within frag
#pragma unroll
          for (int r = 0; r < 4; ++r) {
            float pv = (nb < nbmax) ? sc[nb][r] : 0.0f;
            pch[(q2 * 16 + quad * 4 + r) * 8 + j] = f2bf(pv);
          }
        }
        bf16x8 ap = *(const bf16x8*)&pch[lane * 8];
#pragma unroll
        for (int db = 0; db < 4; ++db) {
          bf16x8 bv = *(const bf16x8*)(Vth + (db * 16 + c) * 512 + kb * 32 + (quad << 3));
          acc[db] = __builtin_amdgcn_mfma_f32_16x16x32_bf16(ap, bv, acc[db], 0, 0, 0);
        }
      }
    }

    // --- normalize + store ctx bf16 [B,S,D] ---
#pragma unroll
    for (int r = 0; r < 4; ++r) {
      float inv = 1.0f / sum[r];
      int row = qbase + quad * 4 + r;
      size_t base = ((size_t)(b * 512 + row)) * 1024 + h * 64;
#pragma unroll
      for (int db = 0; db < 4; ++db)
        ctx[base + db * 16 + c] = f2bf(acc[db][r] * inv);
    }
  }
}

// ---------------------------------------------------------------------------
// Output projection: out = ctx @ w_o^T + b_o  (fp32 out). Same gemm_bt body.
// ---------------------------------------------------------------------------
__global__ __launch_bounds__(256, 2) void gemm_out(const short* __restrict__ ws,
                                                   const float* __restrict__ bias,
                                                   float* __restrict__ out) {
  __shared__ __align__(16) short As[4096];
  __shared__ __align__(16) short Bs[4096];
  int tile = blockIdx.x;            // 0..255
  int mt = tile >> 3, nt = tile & 7;
  int m0 = mt << 7, n0 = nt << 7;
  const short* A  = ws + OFF_CT;
  const short* Bw = ws + OFF_WO;
  int t = threadIdx.x, lane = t & 63, wvi = t >> 6;
  int c = lane & 15, quad = lane >> 4;
  int wm = wvi >> 1, wn = wvi & 1;
  f32x4 acc[4][4] = {};

  for (int kk = 0; kk < 1024; kk += 32) {
#pragma unroll
    for (int i = 0; i < 2; ++i) {
      int ch = wvi * 2 + i;
      async16(&As[ch << 9], A  + (m0 + ch * 16 + c) * 1024 + kk + (quad << 3));
      async16(&Bs[ch << 9], Bw + (n0 + ch * 16 + c) * 1024 + kk + (quad << 3));
    }
    __syncthreads();
    bf16x8 af[4], bfr[4];
#pragma unroll
    for (int i = 0; i < 4; ++i) af[i]  = *(const bf16x8*)&As[((wm * 4 + i) * 64 + lane) * 8];
#pragma unroll
    for (int j = 0; j < 4; ++j) bfr[j] = *(const bf16x8*)&Bs[((wn * 4 + j) * 64 + lane) * 8];
#pragma unroll
    for (int i = 0; i < 4; ++i)
#pragma unroll
      for (int j = 0; j < 4; ++j)
        acc[i][j] = __builtin_amdgcn_mfma_f32_16x16x32_bf16(af[i], bfr[j], acc[i][j], 0, 0, 0);
    __syncthreads();
  }

#pragma unroll
  for (int j = 0; j < 4; ++j) {
    int n = n0 + wn * 64 + j * 16 + c;
    float bj = bias[n];
#pragma unroll
    for (int i = 0; i < 4; ++i) {
      int mq = m0 + wm * 64 + i * 16 + quad * 4;
#pragma unroll
      for (int r = 0; r < 4; ++r)
        out[(size_t)(mq + r) * 1024 + n] = acc[i][j][r] + bj;
    }
  }
}

extern "C" void kernel_launch(void* const* d_in, const int* in_sizes, int n_in,
                              void* d_out, int out_size, void* d_ws, size_t ws_size,
                              hipStream_t stream) {
  (void)in_sizes; (void)n_in; (void)out_size; (void)ws_size;  // needs 48 MB of d_ws
  const float* x  = (const float*)d_in[0];
  const float* wq = (const float*)d_in[1];
  const float* wk = (const float*)d_in[2];
  const float* wv = (const float*)d_in[3];
  const float* wo = (const float*)d_in[4];
  const float* bo = (const float*)d_in[5];
  short* ws = (short*)d_ws;
  float* out = (float*)d_out;

  cvt5<<<8192, 256, 0, stream>>>(x, wq, wk, wv, wo, ws);
  gemm_qkv<<<768, 256, 0, stream>>>(ws);
  attn<<<512, 256, 0, stream>>>(ws);
  gemm_out<<<256, 256, 0, stream>>>(ws, bo, out);
}